// Round 4
// baseline (798.474 us; speedup 1.0000x reference)
//
#include <hip/hip_runtime.h>

// Problem constants
#define B_     4
#define T_     400
#define U_     64
#define E_     320
#define INNER_ 512
#define VOCAB_ 1024
#define M_     (B_ * T_ * U_)   // 102400
#define NROWS_ (B_ * T_ + B_ * U_)  // 1856 projection rows

typedef __attribute__((ext_vector_type(8))) short short8;
typedef __attribute__((ext_vector_type(4))) float f32x4;

__device__ __forceinline__ unsigned short f2bf(float f) {
    union { float f; unsigned u; } v;
    v.f = f;
    unsigned u = v.u;
    u += 0x7fffu + ((u >> 16) & 1u);   // round-to-nearest-even
    return (unsigned short)(u >> 16);
}

__device__ __forceinline__ float tanh_fast(float x) {
    // tanh(x) = 1 - 2/(exp(2x)+1); exp overflow/underflow saturate correctly.
    float e = __expf(2.0f * x);
    return 1.0f - 2.0f / (e + 1.0f);
}

// ---------------------------------------------------------------------------
// Kernel 0: convert W2 (VOCAB x INNER fp32) -> bf16 in workspace.
// ---------------------------------------------------------------------------
__global__ __launch_bounds__(256) void cvt_w2_kernel(
    const float* __restrict__ W2, unsigned short* __restrict__ W2bf) {
    const int i = (blockIdx.x * 256 + threadIdx.x) * 8;
    float4 a = *(const float4*)(W2 + i);
    float4 b = *(const float4*)(W2 + i + 4);
    short8 o;
    o[0] = (short)f2bf(a.x); o[1] = (short)f2bf(a.y);
    o[2] = (short)f2bf(a.z); o[3] = (short)f2bf(a.w);
    o[4] = (short)f2bf(b.x); o[5] = (short)f2bf(b.y);
    o[6] = (short)f2bf(b.z); o[7] = (short)f2bf(b.w);
    *(short8*)(W2bf + i) = o;
}

// ---------------------------------------------------------------------------
// Kernel A: projection, 8 rows per block (232 blocks).
// Rows 0..1599 = enc @ W1[:, :E]^T ; rows 1600..1855 = dec @ W1[:, E:]^T.
// Output fp32 (1856, 512) in workspace. b1 folded into kernel B's tanh.
// ---------------------------------------------------------------------------
__global__ __launch_bounds__(256) void proj_kernel(
    const float* __restrict__ enc,
    const float* __restrict__ dec,
    const float* __restrict__ W1,
    float* __restrict__ proj) {
    __shared__ float xs[8][E_];   // 10240 B
    const int r0 = blockIdx.x * 8;
    const int tid = threadIdx.x;

    for (int i = tid; i < 8 * E_; i += 256) {
        const int rr = i / E_;
        const int cc = i - rr * E_;
        const int row = r0 + rr;
        const float* src = (row < B_ * T_) ? (enc + row * E_)
                                           : (dec + (row - B_ * T_) * E_);
        xs[rr][cc] = src[cc];
    }
    const int colbase = (r0 < B_ * T_) ? 0 : E_;
    __syncthreads();

    for (int o = tid; o < INNER_; o += 256) {   // 2 iterations
        const float* w = W1 + o * (2 * E_) + colbase;
        float acc[8] = {};
        for (int c = 0; c < E_; c += 4) {
            float4 wv = *(const float4*)(w + c);
            #pragma unroll
            for (int rr = 0; rr < 8; ++rr) {
                float4 x = *(const float4*)(&xs[rr][c]);
                acc[rr] += wv.x * x.x + wv.y * x.y + wv.z * x.z + wv.w * x.w;
            }
        }
        #pragma unroll
        for (int rr = 0; rr < 8; ++rr)
            proj[(r0 + rr) * INNER_ + o] = acc[rr];
    }
}

// ---------------------------------------------------------------------------
// Kernel B: fused joint GEMM.
//   A (on the fly) : h[r,k] = tanh(encp[bt,k] + decp[b*64+u,k] + b1[k]) -> bf16
//   B              : W2bf (VOCAB x INNER, bf16 in ws) — B^T layout (K-contig)
//   C              : out (M_ x VOCAB, fp32), + b2
// Block tile 128x128, BK=32, 256 threads = 4 waves in 2x2, each wave 64x64 via
// 4x4 grid of 16x16x32 bf16 MFMAs.
// ---------------------------------------------------------------------------
#define BM  128
#define BN  128
#define BK  32
#define LDA 40   // padded LDS row (bf16 elems)

__global__ __launch_bounds__(256) void joint_kernel(
    const float* __restrict__ encp,
    const float* __restrict__ decp,
    const float* __restrict__ b1,
    const unsigned short* __restrict__ W2bf,
    const float* __restrict__ b2,
    float* __restrict__ out) {
    __shared__ unsigned short As[BM * LDA];
    __shared__ unsigned short Bs[BN * LDA];

    // XCD-aware swizzle: the 8 N-tiles of one M-tile land on one XCD
    // (dispatch heuristic: block i -> XCD i%8) so the proj M-slice is
    // fetched into that XCD's L2 once and reused 8x.
    const int bid = blockIdx.x;
    const int c  = bid & 7;
    const int j  = bid >> 3;          // 0..799
    const int mt = (j & ~7) | c;      // 0..799
    const int nt = j & 7;             // 0..7
    const int m0 = mt * BM;
    const int n0 = nt * BN;

    const int tid  = threadIdx.x;
    const int wid  = tid >> 6;
    const int lane = tid & 63;
    const int wm   = (wid & 1) * 64;
    const int wn   = (wid >> 1) * 64;

    // Staging assignment: 256 threads cover 128 rows x 2 k-halves (16 elems)
    const int sr = tid >> 1;              // 0..127
    const int sk = (tid & 1) * 16;        // 0 or 16
    const int gr = m0 + sr;               // global M row
    const int bt = gr >> 6;               // (b*T + t)
    const int uu = gr & 63;               // u
    const int bb = bt / T_;               // batch index
    const float* eprow = encp + bt * INNER_;
    const float* dprow = decp + (bb * U_ + uu) * INNER_;
    const unsigned short* wrow = W2bf + (size_t)(n0 + sr) * INNER_;

    f32x4 acc[4][4] = {};

    for (int kt = 0; kt < INNER_; kt += BK) {
        // ---- stage A: compute h on the fly, 16 elems/thread ----
        const float* ep = eprow + kt + sk;
        const float* dp = dprow + kt + sk;
        const float* bp = b1 + kt + sk;
        short8 p0, p1;
        #pragma unroll
        for (int i = 0; i < 4; ++i) {
            float4 e4 = *(const float4*)(ep + i * 4);
            float4 d4 = *(const float4*)(dp + i * 4);
            float4 b4 = *(const float4*)(bp + i * 4);
            unsigned short h0 = f2bf(tanh_fast(e4.x + d4.x + b4.x));
            unsigned short h1 = f2bf(tanh_fast(e4.y + d4.y + b4.y));
            unsigned short h2 = f2bf(tanh_fast(e4.z + d4.z + b4.z));
            unsigned short h3 = f2bf(tanh_fast(e4.w + d4.w + b4.w));
            if (i < 2) {
                p0[i * 4 + 0] = (short)h0; p0[i * 4 + 1] = (short)h1;
                p0[i * 4 + 2] = (short)h2; p0[i * 4 + 3] = (short)h3;
            } else {
                p1[(i - 2) * 4 + 0] = (short)h0; p1[(i - 2) * 4 + 1] = (short)h1;
                p1[(i - 2) * 4 + 2] = (short)h2; p1[(i - 2) * 4 + 3] = (short)h3;
            }
        }
        *(short8*)(As + sr * LDA + sk)     = p0;
        *(short8*)(As + sr * LDA + sk + 8) = p1;

        // ---- stage B: bf16 W2 tile copy ----
        short8 w0 = *(const short8*)(wrow + kt + sk);
        short8 w1 = *(const short8*)(wrow + kt + sk + 8);
        *(short8*)(Bs + sr * LDA + sk)     = w0;
        *(short8*)(Bs + sr * LDA + sk + 8) = w1;

        __syncthreads();

        // ---- MFMA: A[m=lane&15][k=(lane>>4)*8 + j] per-lane fragment ----
        const int fr   = lane & 15;
        const int koff = (lane >> 4) * 8;
        short8 af[4], bfr[4];
        #pragma unroll
        for (int i = 0; i < 4; ++i)
            af[i] = *(const short8*)(As + (wm + fr + i * 16) * LDA + koff);
        #pragma unroll
        for (int i = 0; i < 4; ++i)
            bfr[i] = *(const short8*)(Bs + (wn + fr + i * 16) * LDA + koff);
        #pragma unroll
        for (int im = 0; im < 4; ++im)
            #pragma unroll
            for (int in = 0; in < 4; ++in)
                acc[im][in] = __builtin_amdgcn_mfma_f32_16x16x32_bf16(
                    af[im], bfr[in], acc[im][in], 0, 0, 0);

        __syncthreads();
    }

    // ---- epilogue: + b2, fp32 store. C layout: col=lane&15,
    // row=(lane>>4)*4+reg (m89-verified) ----
    const int rq = (lane >> 4) * 4;
    const int cl = lane & 15;
    #pragma unroll
    for (int in = 0; in < 4; ++in) {
        const int col = n0 + wn + in * 16 + cl;
        const float bias = b2[col];
        #pragma unroll
        for (int im = 0; im < 4; ++im) {
            const size_t rbase = (size_t)(m0 + wm + im * 16 + rq);
            #pragma unroll
            for (int r = 0; r < 4; ++r) {
                out[(rbase + r) * VOCAB_ + col] = acc[im][in][r] + bias;
            }
        }
    }
}

extern "C" void kernel_launch(void* const* d_in, const int* in_sizes, int n_in,
                              void* d_out, int out_size, void* d_ws, size_t ws_size,
                              hipStream_t stream) {
    const float* enc = (const float*)d_in[0];  // (4,400,320) fp32
    const float* dec = (const float*)d_in[1];  // (4,64,320)  fp32
    const float* W1  = (const float*)d_in[2];  // (512,640)   fp32
    const float* b1  = (const float*)d_in[3];  // (512,)      fp32
    const float* W2  = (const float*)d_in[4];  // (1024,512)  fp32
    const float* b2  = (const float*)d_in[5];  // (1024,)     fp32
    float* out = (float*)d_out;                // (4,400,64,1024) fp32

    // ws layout: proj fp32 (1856 x 512) = 3,801,088 B, then W2bf (1 MiB)
    float* proj = (float*)d_ws;
    float* encp = proj;                                // rows 0..1599
    float* decp = proj + (size_t)(B_ * T_) * INNER_;   // rows 1600..1855
    unsigned short* W2bf =
        (unsigned short*)((char*)d_ws + (size_t)NROWS_ * INNER_ * sizeof(float));

    cvt_w2_kernel<<<(VOCAB_ * INNER_) / (256 * 8), 256, 0, stream>>>(W2, W2bf);
    proj_kernel<<<NROWS_ / 8, 256, 0, stream>>>(enc, dec, W1, proj);

    const int grid = (M_ / BM) * (VOCAB_ / BN);  // 800 * 8 = 6400
    joint_kernel<<<grid, 256, 0, stream>>>(encp, decp, b1, W2bf, b2, out);
}